// Round 5
// baseline (155.683 us; speedup 1.0000x reference)
//
#include <hip/hip_runtime.h>
#include <hip/hip_bf16.h>
#include <hip/hip_cooperative_groups.h>
#include <math.h>

namespace cg = cooperative_groups;

// Problem dims
#define BB 2
#define LL 2048
#define DD 768
#define HH 12
#define EE 32
#define RR 57
#define NN 20
#define PP 248
#define MM 256          // P padded to 256 for MFMA tiles
#define KS 8            // K-split in context GEMM
#define KCH (LL / KS)   // 256

// ws layout (float offsets)
#define ENT_EMB_OFF 0                          // B*E*D f32
#define A16_OFF   (BB * EE * DD)               // bf16 [B][MM][LL] (unnormalized q)
#define A16_F     (BB * MM * LL / 2)
#define SQT_OFF   (A16_OFF + A16_F)            // bf16 [B][DD][LL]
#define SQT_F     (BB * DD * LL / 2)
#define CPART_OFF (SQT_OFF + SQT_F)            // f32 [KS][B][MM][DD]

#define PT4 4
#define NPT4 62

typedef __attribute__((ext_vector_type(8))) short bf16x8;
typedef __attribute__((ext_vector_type(4))) float f32x4;

__device__ __forceinline__ unsigned short f2bf(float f) {
    __hip_bfloat16 h = __float2bfloat16(f);
    return __builtin_bit_cast(unsigned short, h);
}
__device__ __forceinline__ float bf2f(unsigned short u) {
    unsigned int x = ((unsigned int)u) << 16;
    return __builtin_bit_cast(float, x);
}
__device__ __forceinline__ void pair_so(int p, int& s, int& o) {
    s = p / 31;
    int r = p - s * 31;
    o = (r < s) ? r : r + 1;
}

// One cooperative kernel, 256 blocks x 256 threads, 2 grid syncs.
__global__ __launch_bounds__(256, 1) void mega(const float* __restrict__ seq,
                                               const float* __restrict__ att,
                                               const float* __restrict__ rel,
                                               const float* __restrict__ nota,
                                               const int* __restrict__ spans,
                                               float* __restrict__ ws,
                                               float* __restrict__ out) {
    cg::grid_group grid = cg::this_grid();
    __shared__ __align__(16) char smem[49664];
    int bid = blockIdx.x;
    int t = threadIdx.x;

    // ---- Phase 1a: ent_emb (blocks 0..63) ----
    if (bid < EE * BB) {
        int e = bid & 31, b = bid >> 5;
        int st = spans[b * EE + e];
        float* ee = ws + ENT_EMB_OFF + (size_t)(b * EE + e) * DD;
        const float* srow = seq + (size_t)(b * LL + st) * DD;
        for (int d = t; d < DD; d += 256) {
            ee[d] = 0.25f * (srow[d] + srow[DD + d] + srow[2 * DD + d] + srow[3 * DD + d]);
        }
    }

    // ---- Phase 1b: seqT bf16 cast-transpose, 12 tiles per block ----
    {
        float (*tile)[33] = (float (*)[33])smem;
        int l = t >> 3, c = t & 7;
        int d = t >> 3, j = t & 7;
        #pragma unroll 1
        for (int i = 0; i < 12; ++i) {
            int tt = bid * 12 + i;
            int b = tt / 1536, rem = tt % 1536;
            int l0 = (rem & 63) * 32, d0 = (rem >> 6) * 32;
            float4 v = *(const float4*)(seq + (size_t)(b * LL + l0 + l) * DD + d0 + c * 4);
            __syncthreads();      // protect previous iteration's tile reads
            tile[l][c * 4 + 0] = v.x; tile[l][c * 4 + 1] = v.y;
            tile[l][c * 4 + 2] = v.z; tile[l][c * 4 + 3] = v.w;
            __syncthreads();
            ushort4 o = make_ushort4(f2bf(tile[j * 4 + 0][d]), f2bf(tile[j * 4 + 1][d]),
                                     f2bf(tile[j * 4 + 2][d]), f2bf(tile[j * 4 + 3][d]));
            unsigned short* sqt = (unsigned short*)(ws + SQT_OFF);
            *(ushort4*)(sqt + (size_t)(b * DD + d0 + d) * LL + l0 + j * 4) = o;
        }
    }

    // ---- Phase 2: q pair rows (blocks 0..127, one 32-l chunk each) ----
    if (bid < 128) {
        float (*att_s)[EE * HH + 1] = (float (*)[EE * HH + 1])smem;
        int* sp_s = (int*)(smem + 49280);
        int b = bid >> 6, l0 = (bid & 63) * 32;
        __syncthreads();          // protect P1b's last tile reads (LDS alias)
        if (t < EE) sp_s[t] = spans[b * EE + t];
        __syncthreads();
        for (int i = t; i < EE * HH * 8; i += 256) {
            int seg = i & 7, eh = i >> 3;
            int e = eh / HH, h = eh - e * HH;
            const float* base = att + ((size_t)(b * HH + h) * LL + sp_s[e]) * LL + l0 + seg * 4;
            float4 v0 = *(const float4*)base;
            float4 v1 = *(const float4*)(base + LL);
            float4 v2 = *(const float4*)(base + 2 * LL);
            float4 v3 = *(const float4*)(base + 3 * LL);
            att_s[seg * 4 + 0][eh] = 0.25f * (v0.x + v1.x + v2.x + v3.x);
            att_s[seg * 4 + 1][eh] = 0.25f * (v0.y + v1.y + v2.y + v3.y);
            att_s[seg * 4 + 2][eh] = 0.25f * (v0.z + v1.z + v2.z + v3.z);
            att_s[seg * 4 + 3][eh] = 0.25f * (v0.w + v1.w + v2.w + v3.w);
        }
        __syncthreads();
        int p = t, s, o;
        pair_so(p, s, o);
        float q[32];
        #pragma unroll
        for (int l = 0; l < 32; ++l) {
            float acc = 0.f;
            #pragma unroll
            for (int h = 0; h < HH; ++h) acc += att_s[l][s * HH + h] * att_s[l][o * HH + h];
            q[l] = acc;
        }
        unsigned short* A16 = (unsigned short*)(ws + A16_OFF) + (size_t)(b * MM + p) * LL + l0;
        #pragma unroll
        for (int i = 0; i < 8; ++i) {
            ushort4 ov = make_ushort4(f2bf(q[i * 4 + 0]), f2bf(q[i * 4 + 1]),
                                      f2bf(q[i * 4 + 2]), f2bf(q[i * 4 + 3]));
            *(ushort4*)(A16 + i * 4) = ov;
        }
    }

    grid.sync();

    // ---- Phase 3: context GEMM (bf16 MFMA), 3 tiles per block ----
    {
        short (*As)[40] = (short (*)[40])smem;
        short (*Bs)[40] = (short (*)[40])(smem + 5120);
        int row = t >> 2, seg = t & 3;
        int w = t >> 6, lane = t & 63;
        int wr = w >> 1, wc = w & 1;
        int fr = lane & 15, kb = lane >> 4;
        #pragma unroll 1
        for (int i3 = 0; i3 < 3; ++i3) {
            int tt = bid * 3 + i3;
            int m0 = (tt & 3) * 64;
            int n0 = ((tt >> 2) % 12) * 64;
            int z = tt / 48;
            int ks = z & 7, b = z >> 3;
            const unsigned short* A =
                (const unsigned short*)(ws + A16_OFF) + (size_t)b * MM * LL;
            const unsigned short* Bm =
                (const unsigned short*)(ws + SQT_OFF) + (size_t)b * DD * LL;
            f32x4 acc[2][2] = {};
            int k0c = ks * KCH;
            for (int st = 0; st < KCH / 32; ++st) {
                int kk = k0c + st * 32;
                *(uint4*)&As[row][seg * 8] =
                    *(const uint4*)(A + (size_t)(m0 + row) * LL + kk + seg * 8);
                *(uint4*)&Bs[row][seg * 8] =
                    *(const uint4*)(Bm + (size_t)(n0 + row) * LL + kk + seg * 8);
                __syncthreads();
                bf16x8 af[2], bfr[2];
                #pragma unroll
                for (int i = 0; i < 2; ++i) af[i] = *(bf16x8*)&As[wr * 32 + i * 16 + fr][kb * 8];
                #pragma unroll
                for (int j = 0; j < 2; ++j) bfr[j] = *(bf16x8*)&Bs[wc * 32 + j * 16 + fr][kb * 8];
                #pragma unroll
                for (int i = 0; i < 2; ++i)
                    #pragma unroll
                    for (int j = 0; j < 2; ++j)
                        acc[i][j] = __builtin_amdgcn_mfma_f32_16x16x32_bf16(
                            af[i], bfr[j], acc[i][j], 0, 0, 0);
                __syncthreads();
            }
            float* cp = ws + CPART_OFF + (size_t)((ks * BB + b) * MM) * DD;
            #pragma unroll
            for (int i = 0; i < 2; ++i)
                #pragma unroll
                for (int j = 0; j < 2; ++j)
                    #pragma unroll
                    for (int r = 0; r < 4; ++r) {
                        int gm = m0 + wr * 32 + i * 16 + kb * 4 + r;
                        int gn = n0 + wc * 32 + j * 16 + fr;
                        cp[(size_t)gm * DD + gn] = acc[i][j][r];
                    }
        }
    }

    grid.sync();

    // ---- Phase 4: qsum + register emb + scoring (blocks 0..123) ----
    if (bid < NPT4 * BB) {
        int pt = bid % NPT4, b = bid / NPT4;
        int w = t >> 6, lane = t & 63;
        float (*red_s)[PT4] = (float (*)[PT4])smem;           // [4][4]
        float* qs_s = (float*)(smem + 64);                    // [4]
        float (*nota_s)[NN] = (float (*)[NN])(smem + 128);    // [4][20]
        {
            const unsigned short* A16 =
                (const unsigned short*)(ws + A16_OFF) + (size_t)(b * MM + pt * PT4) * LL;
            #pragma unroll
            for (int j = 0; j < PT4; ++j) {
                ushort4 u0 = *(const ushort4*)(A16 + (size_t)j * LL + t * 8);
                ushort4 u1 = *(const ushort4*)(A16 + (size_t)j * LL + t * 8 + 4);
                float v = bf2f(u0.x) + bf2f(u0.y) + bf2f(u0.z) + bf2f(u0.w)
                        + bf2f(u1.x) + bf2f(u1.y) + bf2f(u1.z) + bf2f(u1.w);
                #pragma unroll
                for (int off = 32; off > 0; off >>= 1) v += __shfl_xor(v, off, 64);
                if (lane == 0) red_s[w][j] = v;
            }
            __syncthreads();
            if (t < PT4)
                qs_s[t] = 1.0f / (red_s[0][t] + red_s[1][t] + red_s[2][t] + red_s[3][t]);
            __syncthreads();
        }
        float4 er[PT4][9];
        #pragma unroll
        for (int j = 0; j < PT4; ++j) {
            int p = pt * PT4 + j;
            int s, o;
            pair_so(p, s, o);
            const float4* es = (const float4*)(ws + ENT_EMB_OFF + (size_t)(b * EE + s) * DD);
            const float4* eo = (const float4*)(ws + ENT_EMB_OFF + (size_t)(b * EE + o) * DD);
            float qs = qs_s[j];
            #pragma unroll
            for (int i4 = 0; i4 < 3; ++i4) er[j][i4] = es[i4 * 64 + lane];
            #pragma unroll
            for (int i4 = 0; i4 < 3; ++i4) er[j][3 + i4] = eo[i4 * 64 + lane];
            #pragma unroll
            for (int i4 = 0; i4 < 3; ++i4) {
                float4 sum = make_float4(0.f, 0.f, 0.f, 0.f);
                #pragma unroll
                for (int ls = 0; ls < KS; ++ls) {
                    const float4* cp = (const float4*)(ws + CPART_OFF +
                                       (size_t)((ls * BB + b) * MM + p) * DD);
                    float4 v = cp[i4 * 64 + lane];
                    sum.x += v.x; sum.y += v.y; sum.z += v.z; sum.w += v.w;
                }
                er[j][6 + i4] = make_float4(sum.x * qs, sum.y * qs, sum.z * qs, sum.w * qs);
            }
        }
        for (int rowi = w; rowi < RR + NN; rowi += 4) {
            const float4* code = (rowi < RR)
                ? (const float4*)(rel + (size_t)rowi * 3 * DD)
                : (const float4*)(nota + (size_t)(rowi - RR) * 3 * DD);
            float acc[PT4] = {0.f, 0.f, 0.f, 0.f};
            #pragma unroll
            for (int i4 = 0; i4 < 9; ++i4) {
                float4 cv = code[i4 * 64 + lane];
                #pragma unroll
                for (int j = 0; j < PT4; ++j) {
                    acc[j] += cv.x * er[j][i4].x + cv.y * er[j][i4].y
                            + cv.z * er[j][i4].z + cv.w * er[j][i4].w;
                }
            }
            #pragma unroll
            for (int j = 0; j < PT4; ++j) {
                float v = acc[j];
                #pragma unroll
                for (int off = 32; off > 0; off >>= 1) v += __shfl_xor(v, off, 64);
                if (lane == 0) {
                    int p = pt * PT4 + j;
                    if (rowi < RR) out[(size_t)(b * PP + p) * (RR + 1) + 1 + rowi] = v;
                    else nota_s[j][rowi - RR] = v;
                }
            }
        }
        __syncthreads();
        if (t < PT4) {
            float m = -INFINITY;
            #pragma unroll
            for (int n = 0; n < NN; ++n) m = fmaxf(m, nota_s[t][n]);
            out[(size_t)(b * PP + pt * PT4 + t) * (RR + 1)] = m;
        }
    }
}

extern "C" void kernel_launch(void* const* d_in, const int* in_sizes, int n_in,
                              void* d_out, int out_size, void* d_ws, size_t ws_size,
                              hipStream_t stream) {
    const float* seq   = (const float*)d_in[0];
    const float* att   = (const float*)d_in[1];
    const float* rel   = (const float*)d_in[2];
    const float* nota  = (const float*)d_in[3];
    const int*   spans = (const int*)d_in[4];
    float* ws  = (float*)d_ws;
    float* out = (float*)d_out;

    void* args[] = {(void*)&seq, (void*)&att, (void*)&rel, (void*)&nota,
                    (void*)&spans, (void*)&ws, (void*)&out};
    hipLaunchCooperativeKernel((const void*)mega, dim3(256), dim3(256), args, 0, stream);
}

// Round 6
// 59.999 us; speedup vs baseline: 2.5947x; 2.5947x over previous
//
#include <hip/hip_runtime.h>
#include <hip/hip_bf16.h>
#include <math.h>

// Problem dims
#define BB 2
#define LL 2048
#define DD 768
#define HH 12
#define EE 32
#define RR 57
#define NN 20
#define PP 248
#define MM 256          // P padded to 256 for MFMA tiles
#define KS 8            // K-split in context GEMM
#define KCH (LL / KS)   // 256

// ws layout (float offsets)
#define ENT_EMB_OFF 0                          // B*E*D f32
#define A16_OFF   (BB * EE * DD)               // bf16 [B][MM][LL] (unnormalized q)
#define A16_F     (BB * MM * LL / 2)
#define SQT_OFF   (A16_OFF + A16_F)            // bf16 [B][DD][LL]
#define SQT_F     (BB * DD * LL / 2)
#define CPART_OFF (SQT_OFF + SQT_F)            // f32 [KS][B][MM][DD]

#define PT4 4
#define NPT4 62

// prep-kernel grid roles
#define NQBLK (BB * 128)          // 256 q blocks (16-l chunks)
#define NEBLK (EE * BB)           // 64 ent_emb blocks
#define NTBLK (BB * 64 * 24)      // 3072 transpose tiles
#define LDS_BYTES (16 * (EE * HH + 1) * 4 + 128)   // att_s + sp_s

typedef __attribute__((ext_vector_type(8))) short bf16x8;
typedef __attribute__((ext_vector_type(4))) float f32x4;

__device__ __forceinline__ unsigned short f2bf(float f) {
    __hip_bfloat16 h = __float2bfloat16(f);
    return __builtin_bit_cast(unsigned short, h);
}
__device__ __forceinline__ float bf2f(unsigned short u) {
    unsigned int x = ((unsigned int)u) << 16;
    return __builtin_bit_cast(float, x);
}
__device__ __forceinline__ void pair_so(int p, int& s, int& o) {
    s = p / 31;
    int r = p - s * 31;
    o = (r < s) ? r : r + 1;
}

// Kernel P (fused prep): role-split, all roles independent (no cross-role deps).
//  bid [0, 256):       q pair rows, one (b, 16-l chunk) each
//  bid [256, 320):     ent_emb
//  bid [320, 3392):    seqT bf16 cast-transpose, one 32x32 tile each
__global__ __launch_bounds__(256) void kP(const float* __restrict__ seq,
                                          const float* __restrict__ att,
                                          const int* __restrict__ spans,
                                          float* __restrict__ ws) {
    __shared__ __align__(16) char smem[LDS_BYTES];
    int bid = blockIdx.x;
    int t = threadIdx.x;

    if (bid < NQBLK) {
        // ---- q: gather+w-average attention into LDS, compute 256 pair rows ----
        float (*att_s)[EE * HH + 1] = (float (*)[EE * HH + 1])smem;
        int* sp_s = (int*)(smem + 16 * (EE * HH + 1) * 4);
        int b = bid >> 7, l0 = (bid & 127) * 16;
        if (t < EE) sp_s[t] = spans[b * EE + t];
        __syncthreads();
        // 384 (e,h) rows x 4 segments of 4 l; average the 4 w-rows inline
        for (int i = t; i < EE * HH * 4; i += 256) {
            int seg = i & 3, eh = i >> 2;
            int e = eh / HH, h = eh - e * HH;
            const float* base = att + ((size_t)(b * HH + h) * LL + sp_s[e]) * LL + l0 + seg * 4;
            float4 v0 = *(const float4*)base;
            float4 v1 = *(const float4*)(base + LL);
            float4 v2 = *(const float4*)(base + 2 * LL);
            float4 v3 = *(const float4*)(base + 3 * LL);
            att_s[seg * 4 + 0][eh] = 0.25f * (v0.x + v1.x + v2.x + v3.x);
            att_s[seg * 4 + 1][eh] = 0.25f * (v0.y + v1.y + v2.y + v3.y);
            att_s[seg * 4 + 2][eh] = 0.25f * (v0.z + v1.z + v2.z + v3.z);
            att_s[seg * 4 + 3][eh] = 0.25f * (v0.w + v1.w + v2.w + v3.w);
        }
        __syncthreads();
        int p = t, s, o;
        pair_so(p, s, o);          // pads p>=248 -> s=8, o<=7: valid indices
        float q[16];
        #pragma unroll
        for (int l = 0; l < 16; ++l) {
            float acc = 0.f;
            #pragma unroll
            for (int h = 0; h < HH; ++h) acc += att_s[l][s * HH + h] * att_s[l][o * HH + h];
            q[l] = acc;
        }
        unsigned short* A16 = (unsigned short*)(ws + A16_OFF) + (size_t)(b * MM + p) * LL + l0;
        #pragma unroll
        for (int i = 0; i < 4; ++i) {
            ushort4 ov = make_ushort4(f2bf(q[i * 4 + 0]), f2bf(q[i * 4 + 1]),
                                      f2bf(q[i * 4 + 2]), f2bf(q[i * 4 + 3]));
            *(ushort4*)(A16 + i * 4) = ov;
        }
    } else if (bid < NQBLK + NEBLK) {
        // ---- ent_emb ----
        int bx = bid - NQBLK;
        int e = bx & 31, b = bx >> 5;
        int st = spans[b * EE + e];
        float* ee = ws + ENT_EMB_OFF + (size_t)(b * EE + e) * DD;
        const float* srow = seq + (size_t)(b * LL + st) * DD;
        for (int d = t; d < DD; d += 256) {
            ee[d] = 0.25f * (srow[d] + srow[DD + d] + srow[2 * DD + d] + srow[3 * DD + d]);
        }
    } else {
        // ---- seqT bf16 cast-transpose, one 32x32 tile ----
        float (*tile)[33] = (float (*)[33])smem;
        int tt = bid - NQBLK - NEBLK;
        int b = tt / 1536, rem = tt % 1536;
        int l0 = (rem & 63) * 32, d0 = (rem >> 6) * 32;
        {
            int l = t >> 3, c = t & 7;
            float4 v = *(const float4*)(seq + (size_t)(b * LL + l0 + l) * DD + d0 + c * 4);
            tile[l][c * 4 + 0] = v.x; tile[l][c * 4 + 1] = v.y;
            tile[l][c * 4 + 2] = v.z; tile[l][c * 4 + 3] = v.w;
        }
        __syncthreads();
        int d = t >> 3, j = t & 7;
        ushort4 o = make_ushort4(f2bf(tile[j * 4 + 0][d]), f2bf(tile[j * 4 + 1][d]),
                                 f2bf(tile[j * 4 + 2][d]), f2bf(tile[j * 4 + 3][d]));
        unsigned short* sqt = (unsigned short*)(ws + SQT_OFF);
        *(ushort4*)(sqt + (size_t)(b * DD + d0 + d) * LL + l0 + j * 4) = o;
    }
}

// Kernel 3: cpart[ks][b][m][n] = sum_{k in split} A[m][k] * seqT[n][k]  (bf16 MFMA)
__global__ __launch_bounds__(256) void k3_gemm(float* __restrict__ ws) {
    int m0 = blockIdx.x * 64, n0 = blockIdx.y * 64;
    int ks = blockIdx.z & (KS - 1), b = blockIdx.z >> 3;
    const unsigned short* A = (const unsigned short*)(ws + A16_OFF) + (size_t)b * MM * LL;
    const unsigned short* Bm = (const unsigned short*)(ws + SQT_OFF) + (size_t)b * DD * LL;
    __shared__ __align__(16) short As[64][40];
    __shared__ __align__(16) short Bs[64][40];
    int t = threadIdx.x;
    int row = t >> 2, seg = t & 3;
    int w = t >> 6, lane = t & 63;
    int wr = w >> 1, wc = w & 1;
    int fr = lane & 15, kb = lane >> 4;
    f32x4 acc[2][2] = {};
    int k0c = ks * KCH;
    for (int st = 0; st < KCH / 32; ++st) {
        int kk = k0c + st * 32;
        *(uint4*)&As[row][seg * 8] = *(const uint4*)(A + (size_t)(m0 + row) * LL + kk + seg * 8);
        *(uint4*)&Bs[row][seg * 8] = *(const uint4*)(Bm + (size_t)(n0 + row) * LL + kk + seg * 8);
        __syncthreads();
        bf16x8 af[2], bfr[2];
        #pragma unroll
        for (int i = 0; i < 2; ++i) af[i] = *(bf16x8*)&As[wr * 32 + i * 16 + fr][kb * 8];
        #pragma unroll
        for (int j = 0; j < 2; ++j) bfr[j] = *(bf16x8*)&Bs[wc * 32 + j * 16 + fr][kb * 8];
        #pragma unroll
        for (int i = 0; i < 2; ++i)
            #pragma unroll
            for (int j = 0; j < 2; ++j)
                acc[i][j] = __builtin_amdgcn_mfma_f32_16x16x32_bf16(af[i], bfr[j], acc[i][j], 0, 0, 0);
        __syncthreads();
    }
    float* cp = ws + CPART_OFF + (size_t)((ks * BB + b) * MM) * DD;
    #pragma unroll
    for (int i = 0; i < 2; ++i)
        #pragma unroll
        for (int j = 0; j < 2; ++j)
            #pragma unroll
            for (int r = 0; r < 4; ++r) {
                int gm = m0 + wr * 32 + i * 16 + kb * 4 + r;
                int gn = n0 + wc * 32 + j * 16 + fr;
                cp[(size_t)gm * DD + gn] = acc[i][j][r];
            }
}

// Kernel 4: qsum + register emb + scoring (2 code rows per iteration for ILP)
__global__ __launch_bounds__(256, 1) void k4_score(const float* __restrict__ rel,
                                                   const float* __restrict__ nota,
                                                   const float* __restrict__ ws,
                                                   float* __restrict__ out) {
    int pt = blockIdx.x, b = blockIdx.y;
    int tid = threadIdx.x, w = tid >> 6, lane = tid & 63;
    __shared__ float red_s[4][PT4];
    __shared__ float qs_s[PT4];
    __shared__ float nota_s[PT4][NN];
    // phase 0: qsum per pair (from bf16 q rows)
    {
        const unsigned short* A16 =
            (const unsigned short*)(ws + A16_OFF) + (size_t)(b * MM + pt * PT4) * LL;
        #pragma unroll
        for (int j = 0; j < PT4; ++j) {
            ushort4 u0 = *(const ushort4*)(A16 + (size_t)j * LL + tid * 8);
            ushort4 u1 = *(const ushort4*)(A16 + (size_t)j * LL + tid * 8 + 4);
            float v = bf2f(u0.x) + bf2f(u0.y) + bf2f(u0.z) + bf2f(u0.w)
                    + bf2f(u1.x) + bf2f(u1.y) + bf2f(u1.z) + bf2f(u1.w);
            #pragma unroll
            for (int off = 32; off > 0; off >>= 1) v += __shfl_xor(v, off, 64);
            if (lane == 0) red_s[w][j] = v;
        }
        __syncthreads();
        if (tid < PT4)
            qs_s[tid] = 1.0f / (red_s[0][tid] + red_s[1][tid] + red_s[2][tid] + red_s[3][tid]);
        __syncthreads();
    }
    // phase 1: per-lane emb fragments for all 4 pairs
    float4 er[PT4][9];
    #pragma unroll
    for (int j = 0; j < PT4; ++j) {
        int p = pt * PT4 + j;
        int s, o;
        pair_so(p, s, o);
        const float4* es = (const float4*)(ws + ENT_EMB_OFF + (size_t)(b * EE + s) * DD);
        const float4* eo = (const float4*)(ws + ENT_EMB_OFF + (size_t)(b * EE + o) * DD);
        float qs = qs_s[j];
        #pragma unroll
        for (int i4 = 0; i4 < 3; ++i4) er[j][i4] = es[i4 * 64 + lane];
        #pragma unroll
        for (int i4 = 0; i4 < 3; ++i4) er[j][3 + i4] = eo[i4 * 64 + lane];
        #pragma unroll
        for (int i4 = 0; i4 < 3; ++i4) {
            float4 sum = make_float4(0.f, 0.f, 0.f, 0.f);
            #pragma unroll
            for (int ls = 0; ls < KS; ++ls) {
                const float4* cp = (const float4*)(ws + CPART_OFF +
                                   (size_t)((ls * BB + b) * MM + p) * DD);
                float4 v = cp[i4 * 64 + lane];
                sum.x += v.x; sum.y += v.y; sum.z += v.z; sum.w += v.w;
            }
            er[j][6 + i4] = make_float4(sum.x * qs, sum.y * qs, sum.z * qs, sum.w * qs);
        }
    }
    // phase 2: 2 code rows per iteration; wave w covers base = 2w + 8k
    for (int base = w * 2; base < RR + NN; base += 8) {
        int r1 = base + 1;
        bool has1 = (r1 < RR + NN);
        const float4* code0 = (base < RR)
            ? (const float4*)(rel + (size_t)base * 3 * DD)
            : (const float4*)(nota + (size_t)(base - RR) * 3 * DD);
        const float4* code1 = has1
            ? ((r1 < RR) ? (const float4*)(rel + (size_t)r1 * 3 * DD)
                         : (const float4*)(nota + (size_t)(r1 - RR) * 3 * DD))
            : code0;
        float acc0[PT4] = {0.f, 0.f, 0.f, 0.f};
        float acc1[PT4] = {0.f, 0.f, 0.f, 0.f};
        #pragma unroll
        for (int i4 = 0; i4 < 9; ++i4) {
            float4 c0 = code0[i4 * 64 + lane];
            float4 c1 = code1[i4 * 64 + lane];
            #pragma unroll
            for (int j = 0; j < PT4; ++j) {
                acc0[j] += c0.x * er[j][i4].x + c0.y * er[j][i4].y
                         + c0.z * er[j][i4].z + c0.w * er[j][i4].w;
                acc1[j] += c1.x * er[j][i4].x + c1.y * er[j][i4].y
                         + c1.z * er[j][i4].z + c1.w * er[j][i4].w;
            }
        }
        #pragma unroll
        for (int j = 0; j < PT4; ++j) {
            float v0 = acc0[j], v1 = acc1[j];
            #pragma unroll
            for (int off = 32; off > 0; off >>= 1) {
                v0 += __shfl_xor(v0, off, 64);
                v1 += __shfl_xor(v1, off, 64);
            }
            if (lane == 0) {
                int p = pt * PT4 + j;
                if (base < RR) out[(size_t)(b * PP + p) * (RR + 1) + 1 + base] = v0;
                else nota_s[j][base - RR] = v0;
                if (has1) {
                    if (r1 < RR) out[(size_t)(b * PP + p) * (RR + 1) + 1 + r1] = v1;
                    else nota_s[j][r1 - RR] = v1;
                }
            }
        }
    }
    __syncthreads();
    if (tid < PT4) {
        float m = -INFINITY;
        #pragma unroll
        for (int n = 0; n < NN; ++n) m = fmaxf(m, nota_s[tid][n]);
        out[(size_t)(b * PP + pt * PT4 + tid) * (RR + 1)] = m;
    }
}

extern "C" void kernel_launch(void* const* d_in, const int* in_sizes, int n_in,
                              void* d_out, int out_size, void* d_ws, size_t ws_size,
                              hipStream_t stream) {
    const float* seq   = (const float*)d_in[0];
    const float* att   = (const float*)d_in[1];
    const float* rel   = (const float*)d_in[2];
    const float* nota  = (const float*)d_in[3];
    const int*   spans = (const int*)d_in[4];
    float* ws  = (float*)d_ws;
    float* out = (float*)d_out;

    kP<<<NQBLK + NEBLK + NTBLK, 256, 0, stream>>>(seq, att, spans, ws);
    k3_gemm<<<dim3(MM / 64, DD / 64, KS * BB), 256, 0, stream>>>(ws);
    k4_score<<<dim3(NPT4, BB), 256, 0, stream>>>(rel, nota, ws, out);
}